// Round 1
// baseline (2018.208 us; speedup 1.0000x reference)
//
#include <hip/hip_runtime.h>

#define B_ 32
#define N_ 8192
#define G_ 512
#define K_ 32
#define EPSF 1e-5f

// ---------------------------------------------------------------------------
// Kernel 1: farthest point sampling. One block per batch, 1024 threads.
// Points staged in LDS (96KB). mindist in registers (8/thread).
// Argmax key: (dist_bits << 13) | (8191 - idx)  -> max-reduce == first-index tiebreak.
// ---------------------------------------------------------------------------
__global__ __launch_bounds__(1024) void fps_kernel(const float* __restrict__ pts,
                                                   float* __restrict__ centers) {
    __shared__ float sx[N_];
    __shared__ float sy[N_];
    __shared__ float sz[N_];
    __shared__ unsigned long long wkeys[16];

    const int b = blockIdx.x;
    const int t = threadIdx.x;
    const float* p = pts + (size_t)b * (N_ * 3);

    for (int i = t; i < N_; i += 1024) {
        sx[i] = p[3 * i + 0];
        sy[i] = p[3 * i + 1];
        sz[i] = p[3 * i + 2];
    }
    float md[8];
#pragma unroll
    for (int j = 0; j < 8; ++j) md[j] = 1e10f;
    __syncthreads();

    int last = 0;
    if (t == 0) {
        float* c = centers + (size_t)b * (G_ * 3);
        c[0] = sx[0]; c[1] = sy[0]; c[2] = sz[0];
    }

    for (int g = 1; g < G_; ++g) {
        const float lx = sx[last], ly = sy[last], lz = sz[last];
        unsigned long long key = 0ull;
#pragma unroll
        for (int j = 0; j < 8; ++j) {
            const int idx = t + j * 1024;
            const float dx = __fsub_rn(sx[idx], lx);
            const float dy = __fsub_rn(sy[idx], ly);
            const float dz = __fsub_rn(sz[idx], lz);
            const float d = __fadd_rn(__fadd_rn(__fmul_rn(dx, dx), __fmul_rn(dy, dy)),
                                      __fmul_rn(dz, dz));
            const float m = fminf(md[j], d);
            md[j] = m;
            const unsigned long long k2 =
                ((unsigned long long)__float_as_uint(m) << 13) |
                (unsigned long long)(unsigned)(8191 - idx);
            key = (key > k2) ? key : k2;
        }
        // wave-level max reduce
#pragma unroll
        for (int off = 32; off >= 1; off >>= 1) {
            const unsigned long long o = __shfl_xor(key, off, 64);
            key = (key > o) ? key : o;
        }
        if ((t & 63) == 0) wkeys[t >> 6] = key;
        __syncthreads();
        unsigned long long best = wkeys[0];
#pragma unroll
        for (int w = 1; w < 16; ++w) {
            const unsigned long long o = wkeys[w];
            best = (best > o) ? best : o;
        }
        last = 8191 - (int)(best & 0x1FFFull);
        if (t == 0) {
            float* c = centers + ((size_t)b * G_ + g) * 3;
            c[0] = sx[last]; c[1] = sy[last]; c[2] = sz[last];
        }
        __syncthreads();  // protect wkeys before next iteration's writes
    }
}

// ---------------------------------------------------------------------------
// Kernel 2: exact kNN (K=32) + grouping. One block (256 thr) per center.
// Each thread caches 32 distance-bit values in registers. 32 rounds of
// block-argmin over cached per-thread minima; the winner excludes its element
// (bitmask) and rescans its 32 regs (static unroll). Key = (bits<<13)|idx,
// min-reduce == smallest dist, then smallest index (lax.top_k stable ties).
// ---------------------------------------------------------------------------
__global__ __launch_bounds__(256) void knn_kernel(const float* __restrict__ pts,
                                                  const float* __restrict__ centers,
                                                  float* __restrict__ neigh) {
    const int cid = blockIdx.x;      // b*512 + g
    const int b = cid >> 9;
    const int t = threadIdx.x;
    const float* p = pts + (size_t)b * (N_ * 3);
    const float* c = centers + (size_t)cid * 3;
    const float cx = c[0], cy = c[1], cz = c[2];

    unsigned int db[32];
#pragma unroll
    for (int i = 0; i < 32; ++i) {
        const int idx = t + (i << 8);
        const float dx = __fsub_rn(p[3 * idx + 0], cx);
        const float dy = __fsub_rn(p[3 * idx + 1], cy);
        const float dz = __fsub_rn(p[3 * idx + 2], cz);
        const float d = __fadd_rn(__fadd_rn(__fmul_rn(dx, dx), __fmul_rn(dy, dy)),
                                  __fmul_rn(dz, dz));
        db[i] = __float_as_uint(d);
    }
    unsigned int excl = 0u;
    unsigned long long lkey = ~0ull;
#pragma unroll
    for (int i = 0; i < 32; ++i) {
        const unsigned long long k2 =
            ((unsigned long long)db[i] << 13) | (unsigned long long)(unsigned)(t + (i << 8));
        lkey = (lkey < k2) ? lkey : k2;
    }

    __shared__ unsigned long long wk[4];
    for (int r = 0; r < K_; ++r) {
        unsigned long long key = lkey;
#pragma unroll
        for (int off = 32; off >= 1; off >>= 1) {
            const unsigned long long o = __shfl_xor(key, off, 64);
            key = (key < o) ? key : o;
        }
        if ((t & 63) == 0) wk[t >> 6] = key;
        __syncthreads();
        unsigned long long best = wk[0];
#pragma unroll
        for (int w = 1; w < 4; ++w) {
            const unsigned long long o = wk[w];
            best = (best < o) ? best : o;
        }
        const int idx = (int)(best & 0x1FFFull);
        if (best == lkey) {  // unique owner (keys contain unique idx)
            excl |= 1u << (idx >> 8);
            unsigned long long nk = ~0ull;
#pragma unroll
            for (int i = 0; i < 32; ++i) {
                if (!(excl & (1u << i))) {
                    const unsigned long long k2 =
                        ((unsigned long long)db[i] << 13) |
                        (unsigned long long)(unsigned)(t + (i << 8));
                    nk = (nk < k2) ? nk : k2;
                }
            }
            lkey = nk;
            float* o3 = neigh + (((size_t)cid * K_) + r) * 3;
            o3[0] = __fsub_rn(p[3 * idx + 0], cx);
            o3[1] = __fsub_rn(p[3 * idx + 1], cy);
            o3[2] = __fsub_rn(p[3 * idx + 2], cz);
        }
        __syncthreads();
    }
}

// ---------------------------------------------------------------------------
// Kernel 3: fused 3-layer MLP (3->64->128->256, bias+BN+ReLU) + global maxpool.
// One block (512 thr) per 64-point tile. h1/h2 in LDS as [channel][point+pad]
// so inner loops read point-vectors with ds_read_b128. Output via integer
// atomicMax on float bits (all values >= 0 after ReLU; d_out zeroed first).
// ---------------------------------------------------------------------------
__global__ __launch_bounds__(512) void mlp_kernel(
    const float* __restrict__ neigh,
    const float* __restrict__ w0, const float* __restrict__ b0,
    const float* __restrict__ g0, const float* __restrict__ be0,
    const float* __restrict__ m0, const float* __restrict__ v0,
    const float* __restrict__ w1, const float* __restrict__ b1,
    const float* __restrict__ g1, const float* __restrict__ be1,
    const float* __restrict__ m1, const float* __restrict__ v1,
    const float* __restrict__ w2, const float* __restrict__ b2,
    const float* __restrict__ g2, const float* __restrict__ be2,
    const float* __restrict__ m2, const float* __restrict__ v2,
    float* __restrict__ out) {
    __shared__ float s_in[64 * 3];
    __shared__ float h1s[64][68];    // [ch][pt+pad]
    __shared__ float h2s[128][68];   // [ch][pt+pad]

    const int t = threadIdx.x;
    const size_t m_base = (size_t)blockIdx.x * 64;
    const int b = (int)(blockIdx.x >> 8);  // 256 blocks per batch (16384 pts / 64)

    for (int i = t; i < 64 * 3; i += 512) s_in[i] = neigh[m_base * 3 + i];
    __syncthreads();

    {  // L1: 3 -> 64
        const int p = t & 63;
        const int og = t >> 6;  // 0..7, wave-uniform
        const float x0 = s_in[p * 3 + 0];
        const float x1 = s_in[p * 3 + 1];
        const float x2 = s_in[p * 3 + 2];
#pragma unroll
        for (int j = 0; j < 8; ++j) {
            const int o = og * 8 + j;
            float acc = x0 * w0[o * 3 + 0] + x1 * w0[o * 3 + 1] + x2 * w0[o * 3 + 2] + b0[o];
            const float sc = g0[o] / sqrtf(v0[o] + EPSF);
            acc = (acc - m0[o]) * sc + be0[o];
            h1s[o][p] = fmaxf(acc, 0.0f);
        }
    }
    __syncthreads();

    {  // L2: 64 -> 128, each thread: 2 out-ch x 8 points
        const int p0 = (t & 7) * 8;
        const int o0 = (t >> 3) * 2;
        float acc0[8] = {0, 0, 0, 0, 0, 0, 0, 0};
        float acc1[8] = {0, 0, 0, 0, 0, 0, 0, 0};
        for (int k = 0; k < 64; ++k) {
            const float4 ha = *(const float4*)&h1s[k][p0];
            const float4 hb = *(const float4*)&h1s[k][p0 + 4];
            const float wa = w1[(o0 + 0) * 64 + k];
            const float wb = w1[(o0 + 1) * 64 + k];
            acc0[0] += wa * ha.x; acc0[1] += wa * ha.y; acc0[2] += wa * ha.z; acc0[3] += wa * ha.w;
            acc0[4] += wa * hb.x; acc0[5] += wa * hb.y; acc0[6] += wa * hb.z; acc0[7] += wa * hb.w;
            acc1[0] += wb * ha.x; acc1[1] += wb * ha.y; acc1[2] += wb * ha.z; acc1[3] += wb * ha.w;
            acc1[4] += wb * hb.x; acc1[5] += wb * hb.y; acc1[6] += wb * hb.z; acc1[7] += wb * hb.w;
        }
        {
            const int o = o0;
            const float sc = g1[o] / sqrtf(v1[o] + EPSF);
            const float bias = b1[o], mm = m1[o], bt = be1[o];
#pragma unroll
            for (int q = 0; q < 8; ++q)
                h2s[o][p0 + q] = fmaxf((acc0[q] + bias - mm) * sc + bt, 0.0f);
        }
        {
            const int o = o0 + 1;
            const float sc = g1[o] / sqrtf(v1[o] + EPSF);
            const float bias = b1[o], mm = m1[o], bt = be1[o];
#pragma unroll
            for (int q = 0; q < 8; ++q)
                h2s[o][p0 + q] = fmaxf((acc1[q] + bias - mm) * sc + bt, 0.0f);
        }
    }
    __syncthreads();

    {  // L3: 128 -> 256, each thread: 4 out-ch x 8 points, then maxpool
        const int p0 = (t & 7) * 8;
        const int o0 = (t >> 3) * 4;
        float acc[4][8];
#pragma unroll
        for (int j = 0; j < 4; ++j)
#pragma unroll
            for (int q = 0; q < 8; ++q) acc[j][q] = 0.0f;

        for (int k = 0; k < 128; ++k) {
            const float4 ha = *(const float4*)&h2s[k][p0];
            const float4 hb = *(const float4*)&h2s[k][p0 + 4];
            const float hv0 = ha.x, hv1 = ha.y, hv2 = ha.z, hv3 = ha.w;
            const float hv4 = hb.x, hv5 = hb.y, hv6 = hb.z, hv7 = hb.w;
#pragma unroll
            for (int j = 0; j < 4; ++j) {
                const float w = w2[(o0 + j) * 128 + k];
                acc[j][0] += w * hv0; acc[j][1] += w * hv1;
                acc[j][2] += w * hv2; acc[j][3] += w * hv3;
                acc[j][4] += w * hv4; acc[j][5] += w * hv5;
                acc[j][6] += w * hv6; acc[j][7] += w * hv7;
            }
        }
#pragma unroll
        for (int j = 0; j < 4; ++j) {
            const int o = o0 + j;
            const float sc = g2[o] / sqrtf(v2[o] + EPSF);
            const float bias = b2[o], mm = m2[o], bt = be2[o];
            float mx = 0.0f;
#pragma unroll
            for (int q = 0; q < 8; ++q) {
                const float v = fmaxf((acc[j][q] + bias - mm) * sc + bt, 0.0f);
                mx = fmaxf(mx, v);
            }
            // reduce over the 8 point-groups (lanes t^1, t^2, t^4 share oq)
            mx = fmaxf(mx, __shfl_xor(mx, 1, 64));
            mx = fmaxf(mx, __shfl_xor(mx, 2, 64));
            mx = fmaxf(mx, __shfl_xor(mx, 4, 64));
            if ((t & 7) == 0)
                atomicMax(reinterpret_cast<unsigned int*>(out) + (b * 256 + o),
                          __float_as_uint(mx));
        }
    }
}

// ---------------------------------------------------------------------------
extern "C" void kernel_launch(void* const* d_in, const int* in_sizes, int n_in,
                              void* d_out, int out_size, void* d_ws, size_t ws_size,
                              hipStream_t stream) {
    const float* pts = (const float*)d_in[0];
    const float* w0 = (const float*)d_in[1];
    const float* b0 = (const float*)d_in[2];
    const float* g0 = (const float*)d_in[3];
    const float* be0 = (const float*)d_in[4];
    const float* m0 = (const float*)d_in[5];
    const float* v0 = (const float*)d_in[6];
    const float* w1 = (const float*)d_in[7];
    const float* b1 = (const float*)d_in[8];
    const float* g1 = (const float*)d_in[9];
    const float* be1 = (const float*)d_in[10];
    const float* m1 = (const float*)d_in[11];
    const float* v1 = (const float*)d_in[12];
    const float* w2 = (const float*)d_in[13];
    const float* b2 = (const float*)d_in[14];
    const float* g2 = (const float*)d_in[15];
    const float* be2 = (const float*)d_in[16];
    const float* m2 = (const float*)d_in[17];
    const float* v2 = (const float*)d_in[18];

    float* centers = (float*)d_ws;                              // 32*512*3*4 = 192KB
    float* neigh = (float*)((char*)d_ws + (size_t)(1 << 18));   // 6.29MB @ 256KB offset

    hipMemsetAsync(d_out, 0, (size_t)out_size * sizeof(float), stream);
    fps_kernel<<<B_, 1024, 0, stream>>>(pts, centers);
    knn_kernel<<<B_ * G_, 256, 0, stream>>>(pts, centers, neigh);
    mlp_kernel<<<(B_ * G_ * K_) / 64, 512, 0, stream>>>(
        neigh, w0, b0, g0, be0, m0, v0, w1, b1, g1, be1, m1, v1,
        w2, b2, g2, be2, m2, v2, (float*)d_out);
}

// Round 2
// 1393.379 us; speedup vs baseline: 1.4484x; 1.4484x over previous
//
#include <hip/hip_runtime.h>

#define B_ 32
#define N_ 8192
#define G_ 512
#define K_ 32
#define EPSF 1e-5f

typedef __attribute__((ext_vector_type(8))) short bf16x8;
typedef __attribute__((ext_vector_type(4))) float f32x4;

static __device__ __forceinline__ short f2bf(float f) {
    unsigned u = __float_as_uint(f);
    u += 0x7fffu + ((u >> 16) & 1u);  // round-to-nearest-even
    return (short)(u >> 16);
}

// ---------------------------------------------------------------------------
// Prep: fold BN (inference) into weights/biases once.  W' = s*W, b' = (b-m)*s+beta.
// W0 stays fp32 as [64][4] = (wx,wy,wz,bias); W1/W2 go to bf16.
// ---------------------------------------------------------------------------
__global__ __launch_bounds__(256) void prep_kernel(
    const float* __restrict__ w0, const float* __restrict__ b0,
    const float* __restrict__ g0, const float* __restrict__ be0,
    const float* __restrict__ m0, const float* __restrict__ v0,
    const float* __restrict__ w1, const float* __restrict__ b1,
    const float* __restrict__ g1, const float* __restrict__ be1,
    const float* __restrict__ m1, const float* __restrict__ v1,
    const float* __restrict__ w2, const float* __restrict__ b2,
    const float* __restrict__ g2, const float* __restrict__ be2,
    const float* __restrict__ m2, const float* __restrict__ v2,
    float* __restrict__ W0b, float* __restrict__ b1b, float* __restrict__ b2b,
    short* __restrict__ W1b, short* __restrict__ W2b) {
    const int t = threadIdx.x;
    if (t < 64) {
        const float sc = g0[t] / sqrtf(v0[t] + EPSF);
        W0b[t * 4 + 0] = w0[t * 3 + 0] * sc;
        W0b[t * 4 + 1] = w0[t * 3 + 1] * sc;
        W0b[t * 4 + 2] = w0[t * 3 + 2] * sc;
        W0b[t * 4 + 3] = (b0[t] - m0[t]) * sc + be0[t];
    }
    if (t < 128) b1b[t] = (b1[t] - m1[t]) * (g1[t] / sqrtf(v1[t] + EPSF)) + be1[t];
    if (t < 256) b2b[t] = (b2[t] - m2[t]) * (g2[t] / sqrtf(v2[t] + EPSF)) + be2[t];
    for (int i = t; i < 128 * 64; i += 256) {
        const int o = i >> 6;
        const float sc = g1[o] / sqrtf(v1[o] + EPSF);
        W1b[i] = f2bf(w1[i] * sc);
    }
    for (int i = t; i < 256 * 128; i += 256) {
        const int o = i >> 7;
        const float sc = g2[o] / sqrtf(v2[o] + EPSF);
        W2b[i] = f2bf(w2[i] * sc);
    }
}

// ---------------------------------------------------------------------------
// Kernel 1: FPS. Points in REGISTERS (8/thread); LDS copy only for the
// winner-coordinate broadcast. One barrier/iter via double-buffered wkeys.
// ---------------------------------------------------------------------------
__global__ __launch_bounds__(1024) void fps_kernel(const float* __restrict__ pts,
                                                   float* __restrict__ centers) {
    __shared__ float sx[N_];
    __shared__ float sy[N_];
    __shared__ float sz[N_];
    __shared__ unsigned long long wkeys[2][16];

    const int b = blockIdx.x;
    const int t = threadIdx.x;
    const float* p = pts + (size_t)b * (N_ * 3);

    float px[8], py[8], pz[8], md[8];
#pragma unroll
    for (int j = 0; j < 8; ++j) {
        const int idx = t + j * 1024;
        px[j] = p[3 * idx + 0];
        py[j] = p[3 * idx + 1];
        pz[j] = p[3 * idx + 2];
        sx[idx] = px[j];
        sy[idx] = py[j];
        sz[idx] = pz[j];
        md[j] = 1e10f;
    }
    __syncthreads();

    if (t == 0) {
        float* c = centers + (size_t)b * (G_ * 3);
        c[0] = sx[0]; c[1] = sy[0]; c[2] = sz[0];
    }
    float lx = sx[0], ly = sy[0], lz = sz[0];

    for (int g = 1; g < G_; ++g) {
        unsigned long long key = 0ull;
#pragma unroll
        for (int j = 0; j < 8; ++j) {
            const int idx = t + j * 1024;
            const float dx = __fsub_rn(px[j], lx);
            const float dy = __fsub_rn(py[j], ly);
            const float dz = __fsub_rn(pz[j], lz);
            const float d = __fadd_rn(__fadd_rn(__fmul_rn(dx, dx), __fmul_rn(dy, dy)),
                                      __fmul_rn(dz, dz));
            const float m = fminf(md[j], d);
            md[j] = m;
            const unsigned long long k2 =
                ((unsigned long long)__float_as_uint(m) << 13) |
                (unsigned long long)(unsigned)(8191 - idx);
            key = (key > k2) ? key : k2;
        }
#pragma unroll
        for (int off = 32; off >= 1; off >>= 1) {
            const unsigned long long o = __shfl_xor(key, off, 64);
            key = (key > o) ? key : o;
        }
        if ((t & 63) == 0) wkeys[g & 1][t >> 6] = key;
        __syncthreads();
        unsigned long long best = wkeys[g & 1][0];
#pragma unroll
        for (int w = 1; w < 16; ++w) {
            const unsigned long long o = wkeys[g & 1][w];
            best = (best > o) ? best : o;
        }
        const int last = 8191 - (int)(best & 0x1FFFull);
        lx = sx[last]; ly = sy[last]; lz = sz[last];
        if (t == 0) {
            float* c = centers + ((size_t)b * G_ + g) * 3;
            c[0] = lx; c[1] = ly; c[2] = lz;
        }
    }
}

// ---------------------------------------------------------------------------
// Kernel 2: exact kNN (K=32) + grouping (unchanged from R1 — passed, not yet
// the bottleneck; counters next round will show it).
// ---------------------------------------------------------------------------
__global__ __launch_bounds__(256) void knn_kernel(const float* __restrict__ pts,
                                                  const float* __restrict__ centers,
                                                  float* __restrict__ neigh) {
    const int cid = blockIdx.x;
    const int b = cid >> 9;
    const int t = threadIdx.x;
    const float* p = pts + (size_t)b * (N_ * 3);
    const float* c = centers + (size_t)cid * 3;
    const float cx = c[0], cy = c[1], cz = c[2];

    unsigned int db[32];
#pragma unroll
    for (int i = 0; i < 32; ++i) {
        const int idx = t + (i << 8);
        const float dx = __fsub_rn(p[3 * idx + 0], cx);
        const float dy = __fsub_rn(p[3 * idx + 1], cy);
        const float dz = __fsub_rn(p[3 * idx + 2], cz);
        const float d = __fadd_rn(__fadd_rn(__fmul_rn(dx, dx), __fmul_rn(dy, dy)),
                                  __fmul_rn(dz, dz));
        db[i] = __float_as_uint(d);
    }
    unsigned int excl = 0u;
    unsigned long long lkey = ~0ull;
#pragma unroll
    for (int i = 0; i < 32; ++i) {
        const unsigned long long k2 =
            ((unsigned long long)db[i] << 13) | (unsigned long long)(unsigned)(t + (i << 8));
        lkey = (lkey < k2) ? lkey : k2;
    }

    __shared__ unsigned long long wk[4];
    for (int r = 0; r < K_; ++r) {
        unsigned long long key = lkey;
#pragma unroll
        for (int off = 32; off >= 1; off >>= 1) {
            const unsigned long long o = __shfl_xor(key, off, 64);
            key = (key < o) ? key : o;
        }
        if ((t & 63) == 0) wk[t >> 6] = key;
        __syncthreads();
        unsigned long long best = wk[0];
#pragma unroll
        for (int w = 1; w < 4; ++w) {
            const unsigned long long o = wk[w];
            best = (best < o) ? best : o;
        }
        const int idx = (int)(best & 0x1FFFull);
        if (best == lkey) {
            excl |= 1u << (idx >> 8);
            unsigned long long nk = ~0ull;
#pragma unroll
            for (int i = 0; i < 32; ++i) {
                if (!(excl & (1u << i))) {
                    const unsigned long long k2 =
                        ((unsigned long long)db[i] << 13) |
                        (unsigned long long)(unsigned)(t + (i << 8));
                    nk = (nk < k2) ? nk : k2;
                }
            }
            lkey = nk;
            float* o3 = neigh + (((size_t)cid * K_) + r) * 3;
            o3[0] = __fsub_rn(p[3 * idx + 0], cx);
            o3[1] = __fsub_rn(p[3 * idx + 1], cy);
            o3[2] = __fsub_rn(p[3 * idx + 2], cz);
        }
        __syncthreads();
    }
}

// ---------------------------------------------------------------------------
// Kernel 3: MFMA MLP. 512 thr (8 waves) x 256 points/block. Each wave owns 32
// rows (2 M-tiles). L2/L3 GEMMs on mfma_f32_16x16x32_bf16. Weights staged to
// LDS with XOR swizzle (linear dest + pre-swizzled global src; reads swizzled).
// h2 redistributed via wave-private swizzled LDS (no block barrier needed).
// ---------------------------------------------------------------------------
__global__ __launch_bounds__(512) void mlp_kernel(
    const float* __restrict__ neigh, const float* __restrict__ W0b,
    const float* __restrict__ b1b, const float* __restrict__ b2b,
    const short* __restrict__ W1b, const short* __restrict__ W2b,
    float* __restrict__ out) {
    __shared__ bf16x8 lw1v[1024];        // 16KB  W1' [128][64] bf16, swizzled
    __shared__ bf16x8 lw2v[4096];        // 64KB  W2' [256][128] bf16, swizzled
    __shared__ bf16x8 lh2v[8 * 512];     // 64KB  per-wave h2 [32][128] bf16, swizzled
    __shared__ float lw0[256];           // 1KB   W0' [64][4] (wx,wy,wz,bias)
    __shared__ float lb1[128];
    __shared__ float lb2[256];
    __shared__ float colmax[256];

    const int t = threadIdx.x;
    const int w = t >> 6;
    const int l = t & 63;
    const int lr = l & 15;   // row/col within 16-tile
    const int lg = l >> 4;   // k-group 0..3

    // ---- stage weights (linear LDS dest, inverse-swizzled global source) ----
    {
        char* d1 = (char*)lw1v;
        for (int i = t; i < 1024; i += 512) {
            const int d = i * 16;
            const int src = d ^ ((((unsigned)d >> 7) & 7) << 4);
            *(bf16x8*)(d1 + d) = *(const bf16x8*)((const char*)W1b + src);
        }
        char* d2 = (char*)lw2v;
        for (int i = t; i < 4096; i += 512) {
            const int d = i * 16;
            const int src = d ^ ((((unsigned)d >> 8) & 7) << 4);
            *(bf16x8*)(d2 + d) = *(const bf16x8*)((const char*)W2b + src);
        }
        if (t < 256) lw0[t] = W0b[t];
        if (t < 128) lb1[t] = b1b[t];
        if (t < 256) lb2[t] = b2b[t];
        if (t < 256) colmax[t] = 0.0f;
    }
    __syncthreads();

    // ---- phase 1: h1 A-fragments in registers (3 -> 64, fp32 then bf16) ----
    const size_t pbase = (size_t)blockIdx.x * 256 + w * 32;
    bf16x8 a1[2][2];  // [mtile][kstep]
#pragma unroll
    for (int m = 0; m < 2; ++m) {
        const float* pp = neigh + (pbase + m * 16 + lr) * 3;
        const float x0 = pp[0], x1 = pp[1], x2 = pp[2];
#pragma unroll
        for (int s = 0; s < 2; ++s) {
            bf16x8 v;
#pragma unroll
            for (int j = 0; j < 8; ++j) {
                const int c = s * 32 + lg * 8 + j;
                const float4 wv = *(const float4*)&lw0[c * 4];
                float val = fmaf(x2, wv.z, fmaf(x1, wv.y, x0 * wv.x)) + wv.w;
                v[j] = f2bf(fmaxf(val, 0.0f));
            }
            a1[m][s] = v;
        }
    }

    // ---- phase 2: L2 GEMM  h2[32][128] = h1[32][64] x W1'^T ----
    const f32x4 vzero = {0.f, 0.f, 0.f, 0.f};
    f32x4 acc2[2][8];
#pragma unroll
    for (int m = 0; m < 2; ++m)
#pragma unroll
        for (int n = 0; n < 8; ++n) acc2[m][n] = vzero;

    const char* w1p = (const char*)lw1v;
#pragma unroll
    for (int s = 0; s < 2; ++s) {
#pragma unroll
        for (int n = 0; n < 8; ++n) {
            const int o = n * 16 + lr;
            int byte = o * 128 + s * 64 + lg * 16;
            byte ^= ((o & 7) << 4);
            const bf16x8 bfr = *(const bf16x8*)(w1p + byte);
            acc2[0][n] = __builtin_amdgcn_mfma_f32_16x16x32_bf16(a1[0][s], bfr, acc2[0][n], 0, 0, 0);
            acc2[1][n] = __builtin_amdgcn_mfma_f32_16x16x32_bf16(a1[1][s], bfr, acc2[1][n], 0, 0, 0);
        }
    }

    // ---- h2 -> wave-private swizzled LDS (bias+ReLU+bf16) ----
    char* myh2 = (char*)(lh2v + w * 512);
#pragma unroll
    for (int m = 0; m < 2; ++m)
#pragma unroll
        for (int n = 0; n < 8; ++n) {
            const int o = n * 16 + lr;
            const float bb = lb1[o];
#pragma unroll
            for (int q = 0; q < 4; ++q) {
                const int row = m * 16 + lg * 4 + q;
                int byte = row * 256 + o * 2;
                byte ^= ((row & 7) << 4);
                *(short*)(myh2 + byte) = f2bf(fmaxf(acc2[m][n][q] + bb, 0.0f));
            }
        }

    // ---- phase 3: L3 GEMM  h3[32][256] = h2[32][128] x W2'^T ----
    f32x4 acc3[2][16];
#pragma unroll
    for (int m = 0; m < 2; ++m)
#pragma unroll
        for (int n = 0; n < 16; ++n) acc3[m][n] = vzero;

    const char* w2p = (const char*)lw2v;
#pragma unroll
    for (int s = 0; s < 4; ++s) {
        bf16x8 a[2];
#pragma unroll
        for (int m = 0; m < 2; ++m) {
            const int row = m * 16 + lr;
            int byte = row * 256 + s * 64 + lg * 16;
            byte ^= ((row & 7) << 4);
            a[m] = *(const bf16x8*)(myh2 + byte);
        }
#pragma unroll
        for (int n = 0; n < 16; ++n) {
            const int o = n * 16 + lr;
            int byte = o * 256 + s * 64 + lg * 16;
            byte ^= ((o & 7) << 4);
            const bf16x8 bfr = *(const bf16x8*)(w2p + byte);
            acc3[0][n] = __builtin_amdgcn_mfma_f32_16x16x32_bf16(a[0], bfr, acc3[0][n], 0, 0, 0);
            acc3[1][n] = __builtin_amdgcn_mfma_f32_16x16x32_bf16(a[1], bfr, acc3[1][n], 0, 0, 0);
        }
    }

    // ---- epilogue: bias+ReLU, max over this wave's 32 rows, block colmax ----
#pragma unroll
    for (int n = 0; n < 16; ++n) {
        const int o = n * 16 + lr;
        const float bb = lb2[o];
        float mx = 0.0f;
#pragma unroll
        for (int m = 0; m < 2; ++m)
#pragma unroll
            for (int q = 0; q < 4; ++q) mx = fmaxf(mx, acc3[m][n][q] + bb);
        mx = fmaxf(mx, 0.0f);  // ReLU (max is vs 0 anyway)
        mx = fmaxf(mx, __shfl_xor(mx, 16, 64));
        mx = fmaxf(mx, __shfl_xor(mx, 32, 64));
        if (lg == 0) atomicMax((unsigned int*)&colmax[o], __float_as_uint(mx));
    }
    __syncthreads();
    if (t < 256) {
        const int b = (int)(blockIdx.x >> 6);  // 64 blocks per batch
        atomicMax((unsigned int*)out + b * 256 + t, __float_as_uint(colmax[t]));
    }
}

// ---------------------------------------------------------------------------
extern "C" void kernel_launch(void* const* d_in, const int* in_sizes, int n_in,
                              void* d_out, int out_size, void* d_ws, size_t ws_size,
                              hipStream_t stream) {
    const float* pts = (const float*)d_in[0];
    const float* w0 = (const float*)d_in[1];
    const float* b0 = (const float*)d_in[2];
    const float* g0 = (const float*)d_in[3];
    const float* be0 = (const float*)d_in[4];
    const float* m0 = (const float*)d_in[5];
    const float* v0 = (const float*)d_in[6];
    const float* w1 = (const float*)d_in[7];
    const float* b1 = (const float*)d_in[8];
    const float* g1 = (const float*)d_in[9];
    const float* be1 = (const float*)d_in[10];
    const float* m1 = (const float*)d_in[11];
    const float* v1 = (const float*)d_in[12];
    const float* w2 = (const float*)d_in[13];
    const float* b2 = (const float*)d_in[14];
    const float* g2 = (const float*)d_in[15];
    const float* be2 = (const float*)d_in[16];
    const float* m2 = (const float*)d_in[17];
    const float* v2 = (const float*)d_in[18];

    char* ws = (char*)d_ws;
    float* centers = (float*)ws;                        // 192KB @ 0
    float* neigh = (float*)(ws + (size_t)262144);       // 6.29MB
    char* wb = ws + (size_t)6553600;                    // weights region
    float* W0b = (float*)(wb + 0);                      // 1KB
    float* b1b = (float*)(wb + 1024);                   // 512B
    float* b2b = (float*)(wb + 1536);                   // 1KB
    short* W1b = (short*)(wb + 2560);                   // 16KB
    short* W2b = (short*)(wb + 2560 + 16384);           // 64KB

    hipMemsetAsync(d_out, 0, (size_t)out_size * sizeof(float), stream);
    prep_kernel<<<1, 256, 0, stream>>>(w0, b0, g0, be0, m0, v0,
                                       w1, b1, g1, be1, m1, v1,
                                       w2, b2, g2, be2, m2, v2,
                                       W0b, b1b, b2b, W1b, W2b);
    fps_kernel<<<B_, 1024, 0, stream>>>(pts, centers);
    knn_kernel<<<B_ * G_, 256, 0, stream>>>(pts, centers, neigh);
    mlp_kernel<<<(B_ * G_ * K_) / 256, 512, 0, stream>>>(
        neigh, W0b, b1b, b2b, W1b, W2b, (float*)d_out);
}

// Round 4
// 1126.660 us; speedup vs baseline: 1.7913x; 1.2367x over previous
//
#include <hip/hip_runtime.h>

#define B_ 32
#define N_ 8192
#define G_ 512
#define K_ 32
#define EPSF 1e-5f

typedef __attribute__((ext_vector_type(8))) short bf16x8;
typedef __attribute__((ext_vector_type(4))) float f32x4;
typedef __attribute__((ext_vector_type(2))) unsigned long long u64x2;

static __device__ __forceinline__ short f2bf(float f) {
    unsigned u = __float_as_uint(f);
    u += 0x7fffu + ((u >> 16) & 1u);  // round-to-nearest-even
    return (short)(u >> 16);
}

static __device__ __forceinline__ unsigned long long u64max(unsigned long long a,
                                                            unsigned long long b) {
    return a > b ? a : b;
}

// DPP row_shr:<N> move of a u64 (two 32-bit mov_dpp, 0-fill on OOB lanes).
// row_shr moves data toward HIGHER lanes (lane i receives lane i-N); after
// shr 1,2,4,8 the 16-lane row max lands in lane 15 of each row (rocPRIM idiom).
// For max-reduce of non-negative keys, the 0-fill is neutral.
template <int CTL>
static __device__ __forceinline__ unsigned long long dpp_shr_u64(unsigned long long k) {
    const int lo = __builtin_amdgcn_mov_dpp((int)(unsigned)k, CTL, 0xf, 0xf, true);
    const int hi = __builtin_amdgcn_mov_dpp((int)(unsigned)(k >> 32), CTL, 0xf, 0xf, true);
    return ((unsigned long long)(unsigned)hi << 32) | (unsigned)lo;
}

// ---------------------------------------------------------------------------
// Prep: fold BN (inference) into weights/biases once.
// ---------------------------------------------------------------------------
__global__ __launch_bounds__(256) void prep_kernel(
    const float* __restrict__ w0, const float* __restrict__ b0,
    const float* __restrict__ g0, const float* __restrict__ be0,
    const float* __restrict__ m0, const float* __restrict__ v0,
    const float* __restrict__ w1, const float* __restrict__ b1,
    const float* __restrict__ g1, const float* __restrict__ be1,
    const float* __restrict__ m1, const float* __restrict__ v1,
    const float* __restrict__ w2, const float* __restrict__ b2,
    const float* __restrict__ g2, const float* __restrict__ be2,
    const float* __restrict__ m2, const float* __restrict__ v2,
    float* __restrict__ W0b, float* __restrict__ b1b, float* __restrict__ b2b,
    short* __restrict__ W1b, short* __restrict__ W2b) {
    const int t = threadIdx.x;
    if (t < 64) {
        const float sc = g0[t] / sqrtf(v0[t] + EPSF);
        W0b[t * 4 + 0] = w0[t * 3 + 0] * sc;
        W0b[t * 4 + 1] = w0[t * 3 + 1] * sc;
        W0b[t * 4 + 2] = w0[t * 3 + 2] * sc;
        W0b[t * 4 + 3] = (b0[t] - m0[t]) * sc + be0[t];
    }
    if (t < 128) b1b[t] = (b1[t] - m1[t]) * (g1[t] / sqrtf(v1[t] + EPSF)) + be1[t];
    if (t < 256) b2b[t] = (b2[t] - m2[t]) * (g2[t] / sqrtf(v2[t] + EPSF)) + be2[t];
    for (int i = t; i < 128 * 64; i += 256) {
        const int o = i >> 6;
        const float sc = g1[o] / sqrtf(v1[o] + EPSF);
        W1b[i] = f2bf(w1[i] * sc);
    }
    for (int i = t; i < 256 * 128; i += 256) {
        const int o = i >> 7;
        const float sc = g2[o] / sqrtf(v2[o] + EPSF);
        W2b[i] = f2bf(w2[i] * sc);
    }
}

// ---------------------------------------------------------------------------
// Kernel 1: FPS v3 fixed — row_shr reduce lands in lane 15 (not lane 0).
// Stage 1: per-row DPP reduce, lane 15/31/47/63 write 4 row-keys per wave.
// Stage 2: each wave redundantly reduces the 32 row-keys (1 ds_read_b128 per
// lane over pairs + 4 DPP levels), winner extracted with readlane(.., 15).
// Key = (dist_bits<<13) | (8191-idx): max-reduce == argmax, first-index ties.
// ---------------------------------------------------------------------------
__global__ __launch_bounds__(512) void fps_kernel(const float* __restrict__ pts,
                                                  float* __restrict__ centers) {
    __shared__ float4 sxyz[N_];  // 128KB
    __shared__ __align__(16) unsigned long long rowkeys[2][32];

    const int b = blockIdx.x;
    const int t = threadIdx.x;
    const int l = t & 63;
    const int w = t >> 6;
    const float* p = pts + (size_t)b * (N_ * 3);

    float px[16], py[16], pz[16], md[16];
#pragma unroll
    for (int j = 0; j < 16; ++j) {
        const int idx = t + j * 512;
        px[j] = p[3 * idx + 0];
        py[j] = p[3 * idx + 1];
        pz[j] = p[3 * idx + 2];
        sxyz[idx] = make_float4(px[j], py[j], pz[j], 0.0f);
        md[j] = 1e10f;
    }
    __syncthreads();

    if (t == 0) {
        float* c = centers + (size_t)b * (G_ * 3);
        c[0] = px[0]; c[1] = py[0]; c[2] = pz[0];  // idx 0
    }
    float4 c0 = sxyz[0];
    float lx = c0.x, ly = c0.y, lz = c0.z;
    const int pay0 = 8191 - t;

    for (int g = 1; g < G_; ++g) {
        float m_best = -1.0f;
        int j_best = 0;
#pragma unroll
        for (int j = 0; j < 16; ++j) {
            const float dx = __fsub_rn(px[j], lx);
            const float dy = __fsub_rn(py[j], ly);
            const float dz = __fsub_rn(pz[j], lz);
            const float d = __fadd_rn(__fadd_rn(__fmul_rn(dx, dx), __fmul_rn(dy, dy)),
                                      __fmul_rn(dz, dz));
            const float m = fminf(md[j], d);
            md[j] = m;
            const bool c = m > m_best;  // strict: keeps smallest j on ties
            m_best = c ? m : m_best;
            j_best = c ? j : j_best;
        }
        unsigned long long key =
            ((unsigned long long)__float_as_uint(m_best) << 13) |
            (unsigned long long)(unsigned)(pay0 - (j_best << 9));

        // wave-level reduce within 16-lane rows (DPP, no DS traffic);
        // row max accumulates into lane 15 of each row
        key = u64max(key, dpp_shr_u64<0x111>(key));
        key = u64max(key, dpp_shr_u64<0x112>(key));
        key = u64max(key, dpp_shr_u64<0x114>(key));
        key = u64max(key, dpp_shr_u64<0x118>(key));
        if ((l & 15) == 15) rowkeys[g & 1][w * 4 + (l >> 4)] = key;  // 4 rows/wave
        __syncthreads();

        // block reduce, redundantly per wave: 32 keys via b128 pairs;
        // every 16-lane row covers all 32 keys, winner lands in lane 15
        const u64x2* rk = (const u64x2*)&rowkeys[g & 1][0];
        const u64x2 k2 = rk[l & 15];
        unsigned long long kk = u64max(k2[0], k2[1]);
        kk = u64max(kk, dpp_shr_u64<0x111>(kk));
        kk = u64max(kk, dpp_shr_u64<0x112>(kk));
        kk = u64max(kk, dpp_shr_u64<0x114>(kk));
        kk = u64max(kk, dpp_shr_u64<0x118>(kk));
        const unsigned blo =
            (unsigned)__builtin_amdgcn_readlane((int)(unsigned)kk, 15);
        const int last = 8191 - (int)(blo & 0x1FFFu);

        const float4 cc = sxyz[last];  // broadcast read
        lx = cc.x; ly = cc.y; lz = cc.z;
        if (t == 0) {
            float* c = centers + ((size_t)b * G_ + g) * 3;
            c[0] = lx; c[1] = ly; c[2] = lz;
        }
    }
}

// ---------------------------------------------------------------------------
// Kernel 2: exact kNN (K=32) + grouping. Double-buffered wk -> 1 barrier/round.
// ---------------------------------------------------------------------------
__global__ __launch_bounds__(256) void knn_kernel(const float* __restrict__ pts,
                                                  const float* __restrict__ centers,
                                                  float* __restrict__ neigh) {
    const int cid = blockIdx.x;
    const int b = cid >> 9;
    const int t = threadIdx.x;
    const float* p = pts + (size_t)b * (N_ * 3);
    const float* c = centers + (size_t)cid * 3;
    const float cx = c[0], cy = c[1], cz = c[2];

    unsigned int db[32];
#pragma unroll
    for (int i = 0; i < 32; ++i) {
        const int idx = t + (i << 8);
        const float dx = __fsub_rn(p[3 * idx + 0], cx);
        const float dy = __fsub_rn(p[3 * idx + 1], cy);
        const float dz = __fsub_rn(p[3 * idx + 2], cz);
        const float d = __fadd_rn(__fadd_rn(__fmul_rn(dx, dx), __fmul_rn(dy, dy)),
                                  __fmul_rn(dz, dz));
        db[i] = __float_as_uint(d);
    }
    unsigned int excl = 0u;
    unsigned long long lkey = ~0ull;
#pragma unroll
    for (int i = 0; i < 32; ++i) {
        const unsigned long long k2 =
            ((unsigned long long)db[i] << 13) | (unsigned long long)(unsigned)(t + (i << 8));
        lkey = (lkey < k2) ? lkey : k2;
    }

    __shared__ unsigned long long wk[2][4];
    for (int r = 0; r < K_; ++r) {
        unsigned long long key = lkey;
#pragma unroll
        for (int off = 32; off >= 1; off >>= 1) {
            const unsigned long long o = __shfl_xor(key, off, 64);
            key = (key < o) ? key : o;
        }
        if ((t & 63) == 0) wk[r & 1][t >> 6] = key;
        __syncthreads();
        unsigned long long best = wk[r & 1][0];
#pragma unroll
        for (int ww = 1; ww < 4; ++ww) {
            const unsigned long long o = wk[r & 1][ww];
            best = (best < o) ? best : o;
        }
        const int idx = (int)(best & 0x1FFFull);
        if (best == lkey) {  // unique owner (keys contain unique idx)
            excl |= 1u << (idx >> 8);
            unsigned long long nk = ~0ull;
#pragma unroll
            for (int i = 0; i < 32; ++i) {
                if (!(excl & (1u << i))) {
                    const unsigned long long k2 =
                        ((unsigned long long)db[i] << 13) |
                        (unsigned long long)(unsigned)(t + (i << 8));
                    nk = (nk < k2) ? nk : k2;
                }
            }
            lkey = nk;
            float* o3 = neigh + (((size_t)cid * K_) + r) * 3;
            o3[0] = __fsub_rn(p[3 * idx + 0], cx);
            o3[1] = __fsub_rn(p[3 * idx + 1], cy);
            o3[2] = __fsub_rn(p[3 * idx + 2], cz);
        }
        // no trailing barrier: wk is double-buffered on r&1
    }
}

// ---------------------------------------------------------------------------
// Kernel 3: MFMA MLP (unchanged from R2). 512 thr x 256 points/block.
// ---------------------------------------------------------------------------
__global__ __launch_bounds__(512) void mlp_kernel(
    const float* __restrict__ neigh, const float* __restrict__ W0b,
    const float* __restrict__ b1b, const float* __restrict__ b2b,
    const short* __restrict__ W1b, const short* __restrict__ W2b,
    float* __restrict__ out) {
    __shared__ bf16x8 lw1v[1024];        // 16KB  W1' [128][64] bf16, swizzled
    __shared__ bf16x8 lw2v[4096];        // 64KB  W2' [256][128] bf16, swizzled
    __shared__ bf16x8 lh2v[8 * 512];     // 64KB  per-wave h2 [32][128] bf16, swizzled
    __shared__ float lw0[256];           // 1KB   W0' [64][4] (wx,wy,wz,bias)
    __shared__ float lb1[128];
    __shared__ float lb2[256];
    __shared__ float colmax[256];

    const int t = threadIdx.x;
    const int w = t >> 6;
    const int l = t & 63;
    const int lr = l & 15;   // row/col within 16-tile
    const int lg = l >> 4;   // k-group 0..3

    {
        char* d1 = (char*)lw1v;
        for (int i = t; i < 1024; i += 512) {
            const int d = i * 16;
            const int src = d ^ ((((unsigned)d >> 7) & 7) << 4);
            *(bf16x8*)(d1 + d) = *(const bf16x8*)((const char*)W1b + src);
        }
        char* d2 = (char*)lw2v;
        for (int i = t; i < 4096; i += 512) {
            const int d = i * 16;
            const int src = d ^ ((((unsigned)d >> 8) & 7) << 4);
            *(bf16x8*)(d2 + d) = *(const bf16x8*)((const char*)W2b + src);
        }
        if (t < 256) lw0[t] = W0b[t];
        if (t < 128) lb1[t] = b1b[t];
        if (t < 256) lb2[t] = b2b[t];
        if (t < 256) colmax[t] = 0.0f;
    }
    __syncthreads();

    const size_t pbase = (size_t)blockIdx.x * 256 + w * 32;
    bf16x8 a1[2][2];  // [mtile][kstep]
#pragma unroll
    for (int m = 0; m < 2; ++m) {
        const float* pp = neigh + (pbase + m * 16 + lr) * 3;
        const float x0 = pp[0], x1 = pp[1], x2 = pp[2];
#pragma unroll
        for (int s = 0; s < 2; ++s) {
            bf16x8 v;
#pragma unroll
            for (int j = 0; j < 8; ++j) {
                const int c = s * 32 + lg * 8 + j;
                const float4 wv = *(const float4*)&lw0[c * 4];
                float val = fmaf(x2, wv.z, fmaf(x1, wv.y, x0 * wv.x)) + wv.w;
                v[j] = f2bf(fmaxf(val, 0.0f));
            }
            a1[m][s] = v;
        }
    }

    const f32x4 vzero = {0.f, 0.f, 0.f, 0.f};
    f32x4 acc2[2][8];
#pragma unroll
    for (int m = 0; m < 2; ++m)
#pragma unroll
        for (int n = 0; n < 8; ++n) acc2[m][n] = vzero;

    const char* w1p = (const char*)lw1v;
#pragma unroll
    for (int s = 0; s < 2; ++s) {
#pragma unroll
        for (int n = 0; n < 8; ++n) {
            const int o = n * 16 + lr;
            int byte = o * 128 + s * 64 + lg * 16;
            byte ^= ((o & 7) << 4);
            const bf16x8 bfr = *(const bf16x8*)(w1p + byte);
            acc2[0][n] = __builtin_amdgcn_mfma_f32_16x16x32_bf16(a1[0][s], bfr, acc2[0][n], 0, 0, 0);
            acc2[1][n] = __builtin_amdgcn_mfma_f32_16x16x32_bf16(a1[1][s], bfr, acc2[1][n], 0, 0, 0);
        }
    }

    char* myh2 = (char*)(lh2v + w * 512);
#pragma unroll
    for (int m = 0; m < 2; ++m)
#pragma unroll
        for (int n = 0; n < 8; ++n) {
            const int o = n * 16 + lr;
            const float bb = lb1[o];
#pragma unroll
            for (int q = 0; q < 4; ++q) {
                const int row = m * 16 + lg * 4 + q;
                int byte = row * 256 + o * 2;
                byte ^= ((row & 7) << 4);
                *(short*)(myh2 + byte) = f2bf(fmaxf(acc2[m][n][q] + bb, 0.0f));
            }
        }

    f32x4 acc3[2][16];
#pragma unroll
    for (int m = 0; m < 2; ++m)
#pragma unroll
        for (int n = 0; n < 16; ++n) acc3[m][n] = vzero;

    const char* w2p = (const char*)lw2v;
#pragma unroll
    for (int s = 0; s < 4; ++s) {
        bf16x8 a[2];
#pragma unroll
        for (int m = 0; m < 2; ++m) {
            const int row = m * 16 + lr;
            int byte = row * 256 + s * 64 + lg * 16;
            byte ^= ((row & 7) << 4);
            a[m] = *(const bf16x8*)(myh2 + byte);
        }
#pragma unroll
        for (int n = 0; n < 16; ++n) {
            const int o = n * 16 + lr;
            int byte = o * 256 + s * 64 + lg * 16;
            byte ^= ((o & 7) << 4);
            const bf16x8 bfr = *(const bf16x8*)(w2p + byte);
            acc3[0][n] = __builtin_amdgcn_mfma_f32_16x16x32_bf16(a[0], bfr, acc3[0][n], 0, 0, 0);
            acc3[1][n] = __builtin_amdgcn_mfma_f32_16x16x32_bf16(a[1], bfr, acc3[1][n], 0, 0, 0);
        }
    }

#pragma unroll
    for (int n = 0; n < 16; ++n) {
        const int o = n * 16 + lr;
        const float bb = lb2[o];
        float mx = 0.0f;
#pragma unroll
        for (int m = 0; m < 2; ++m)
#pragma unroll
            for (int q = 0; q < 4; ++q) mx = fmaxf(mx, acc3[m][n][q] + bb);
        mx = fmaxf(mx, 0.0f);
        mx = fmaxf(mx, __shfl_xor(mx, 16, 64));
        mx = fmaxf(mx, __shfl_xor(mx, 32, 64));
        if (lg == 0) atomicMax((unsigned int*)&colmax[o], __float_as_uint(mx));
    }
    __syncthreads();
    if (t < 256) {
        const int b = (int)(blockIdx.x >> 6);  // 64 blocks per batch
        atomicMax((unsigned int*)out + b * 256 + t, __float_as_uint(colmax[t]));
    }
}

// ---------------------------------------------------------------------------
extern "C" void kernel_launch(void* const* d_in, const int* in_sizes, int n_in,
                              void* d_out, int out_size, void* d_ws, size_t ws_size,
                              hipStream_t stream) {
    const float* pts = (const float*)d_in[0];
    const float* w0 = (const float*)d_in[1];
    const float* b0 = (const float*)d_in[2];
    const float* g0 = (const float*)d_in[3];
    const float* be0 = (const float*)d_in[4];
    const float* m0 = (const float*)d_in[5];
    const float* v0 = (const float*)d_in[6];
    const float* w1 = (const float*)d_in[7];
    const float* b1 = (const float*)d_in[8];
    const float* g1 = (const float*)d_in[9];
    const float* be1 = (const float*)d_in[10];
    const float* m1 = (const float*)d_in[11];
    const float* v1 = (const float*)d_in[12];
    const float* w2 = (const float*)d_in[13];
    const float* b2 = (const float*)d_in[14];
    const float* g2 = (const float*)d_in[15];
    const float* be2 = (const float*)d_in[16];
    const float* m2 = (const float*)d_in[17];
    const float* v2 = (const float*)d_in[18];

    char* ws = (char*)d_ws;
    float* centers = (float*)ws;                        // 192KB @ 0
    float* neigh = (float*)(ws + (size_t)262144);       // 6.29MB
    char* wb = ws + (size_t)6553600;                    // weights region
    float* W0b = (float*)(wb + 0);                      // 1KB
    float* b1b = (float*)(wb + 1024);                   // 512B
    float* b2b = (float*)(wb + 1536);                   // 1KB
    short* W1b = (short*)(wb + 2560);                   // 16KB
    short* W2b = (short*)(wb + 2560 + 16384);           // 64KB

    hipMemsetAsync(d_out, 0, (size_t)out_size * sizeof(float), stream);
    prep_kernel<<<1, 256, 0, stream>>>(w0, b0, g0, be0, m0, v0,
                                       w1, b1, g1, be1, m1, v1,
                                       w2, b2, g2, be2, m2, v2,
                                       W0b, b1b, b2b, W1b, W2b);
    fps_kernel<<<B_, 512, 0, stream>>>(pts, centers);
    knn_kernel<<<B_ * G_, 256, 0, stream>>>(pts, centers, neigh);
    mlp_kernel<<<(B_ * G_ * K_) / 256, 512, 0, stream>>>(
        neigh, W0b, b1b, b2b, W1b, W2b, (float*)d_out);
}

// Round 5
// 928.358 us; speedup vs baseline: 2.1740x; 1.2136x over previous
//
#include <hip/hip_runtime.h>

#define B_ 32
#define N_ 8192
#define G_ 512
#define K_ 32
#define EPSF 1e-5f

typedef __attribute__((ext_vector_type(8))) short bf16x8;
typedef __attribute__((ext_vector_type(4))) float f32x4;
typedef __attribute__((ext_vector_type(2))) unsigned long long u64x2;

static __device__ __forceinline__ short f2bf(float f) {
    unsigned u = __float_as_uint(f);
    u += 0x7fffu + ((u >> 16) & 1u);  // round-to-nearest-even
    return (short)(u >> 16);
}

static __device__ __forceinline__ unsigned long long u64max(unsigned long long a,
                                                            unsigned long long b) {
    return a > b ? a : b;
}
static __device__ __forceinline__ unsigned long long u64min(unsigned long long a,
                                                            unsigned long long b) {
    return a < b ? a : b;
}

// DPP row_shr:<N> move of a u64, 0-fill (max-neutral for non-negative keys).
template <int CTL>
static __device__ __forceinline__ unsigned long long dpp_shr_u64(unsigned long long k) {
    const int lo = __builtin_amdgcn_mov_dpp((int)(unsigned)k, CTL, 0xf, 0xf, true);
    const int hi = __builtin_amdgcn_mov_dpp((int)(unsigned)(k >> 32), CTL, 0xf, 0xf, true);
    return ((unsigned long long)(unsigned)hi << 32) | (unsigned)lo;
}

// DPP move of a u64 that PRESERVES the old value on unwritten/invalid lanes
// (bound_ctrl=false, old=own key) -> safe for MIN reductions (no 0-fill).
template <int CTL>
static __device__ __forceinline__ unsigned long long dpp_upd_u64(unsigned long long k) {
    const int lo = __builtin_amdgcn_update_dpp((int)(unsigned)k, (int)(unsigned)k,
                                               CTL, 0xf, 0xf, false);
    const int hi = __builtin_amdgcn_update_dpp((int)(unsigned)(k >> 32),
                                               (int)(unsigned)(k >> 32),
                                               CTL, 0xf, 0xf, false);
    return ((unsigned long long)(unsigned)hi << 32) | (unsigned)lo;
}

// ---------------------------------------------------------------------------
// Prep: fold BN (inference) into weights/biases once.
// ---------------------------------------------------------------------------
__global__ __launch_bounds__(256) void prep_kernel(
    const float* __restrict__ w0, const float* __restrict__ b0,
    const float* __restrict__ g0, const float* __restrict__ be0,
    const float* __restrict__ m0, const float* __restrict__ v0,
    const float* __restrict__ w1, const float* __restrict__ b1,
    const float* __restrict__ g1, const float* __restrict__ be1,
    const float* __restrict__ m1, const float* __restrict__ v1,
    const float* __restrict__ w2, const float* __restrict__ b2,
    const float* __restrict__ g2, const float* __restrict__ be2,
    const float* __restrict__ m2, const float* __restrict__ v2,
    float* __restrict__ W0b, float* __restrict__ b1b, float* __restrict__ b2b,
    short* __restrict__ W1b, short* __restrict__ W2b) {
    const int t = threadIdx.x;
    if (t < 64) {
        const float sc = g0[t] / sqrtf(v0[t] + EPSF);
        W0b[t * 4 + 0] = w0[t * 3 + 0] * sc;
        W0b[t * 4 + 1] = w0[t * 3 + 1] * sc;
        W0b[t * 4 + 2] = w0[t * 3 + 2] * sc;
        W0b[t * 4 + 3] = (b0[t] - m0[t]) * sc + be0[t];
    }
    if (t < 128) b1b[t] = (b1[t] - m1[t]) * (g1[t] / sqrtf(v1[t] + EPSF)) + be1[t];
    if (t < 256) b2b[t] = (b2[t] - m2[t]) * (g2[t] / sqrtf(v2[t] + EPSF)) + be2[t];
    for (int i = t; i < 128 * 64; i += 256) {
        const int o = i >> 6;
        const float sc = g1[o] / sqrtf(v1[o] + EPSF);
        W1b[i] = f2bf(w1[i] * sc);
    }
    for (int i = t; i < 256 * 128; i += 256) {
        const int o = i >> 7;
        const float sc = g2[o] / sqrtf(v2[o] + EPSF);
        W2b[i] = f2bf(w2[i] * sc);
    }
}

// ---------------------------------------------------------------------------
// Kernel 1: FPS (unchanged from R4 — passed).
// ---------------------------------------------------------------------------
__global__ __launch_bounds__(512) void fps_kernel(const float* __restrict__ pts,
                                                  float* __restrict__ centers) {
    __shared__ float4 sxyz[N_];  // 128KB
    __shared__ __align__(16) unsigned long long rowkeys[2][32];

    const int b = blockIdx.x;
    const int t = threadIdx.x;
    const int l = t & 63;
    const int w = t >> 6;
    const float* p = pts + (size_t)b * (N_ * 3);

    float px[16], py[16], pz[16], md[16];
#pragma unroll
    for (int j = 0; j < 16; ++j) {
        const int idx = t + j * 512;
        px[j] = p[3 * idx + 0];
        py[j] = p[3 * idx + 1];
        pz[j] = p[3 * idx + 2];
        sxyz[idx] = make_float4(px[j], py[j], pz[j], 0.0f);
        md[j] = 1e10f;
    }
    __syncthreads();

    if (t == 0) {
        float* c = centers + (size_t)b * (G_ * 3);
        c[0] = px[0]; c[1] = py[0]; c[2] = pz[0];
    }
    float4 c0 = sxyz[0];
    float lx = c0.x, ly = c0.y, lz = c0.z;
    const int pay0 = 8191 - t;

    for (int g = 1; g < G_; ++g) {
        float m_best = -1.0f;
        int j_best = 0;
#pragma unroll
        for (int j = 0; j < 16; ++j) {
            const float dx = __fsub_rn(px[j], lx);
            const float dy = __fsub_rn(py[j], ly);
            const float dz = __fsub_rn(pz[j], lz);
            const float d = __fadd_rn(__fadd_rn(__fmul_rn(dx, dx), __fmul_rn(dy, dy)),
                                      __fmul_rn(dz, dz));
            const float m = fminf(md[j], d);
            md[j] = m;
            const bool c = m > m_best;
            m_best = c ? m : m_best;
            j_best = c ? j : j_best;
        }
        unsigned long long key =
            ((unsigned long long)__float_as_uint(m_best) << 13) |
            (unsigned long long)(unsigned)(pay0 - (j_best << 9));

        key = u64max(key, dpp_shr_u64<0x111>(key));
        key = u64max(key, dpp_shr_u64<0x112>(key));
        key = u64max(key, dpp_shr_u64<0x114>(key));
        key = u64max(key, dpp_shr_u64<0x118>(key));
        if ((l & 15) == 15) rowkeys[g & 1][w * 4 + (l >> 4)] = key;
        __syncthreads();

        const u64x2* rk = (const u64x2*)&rowkeys[g & 1][0];
        const u64x2 k2 = rk[l & 15];
        unsigned long long kk = u64max(k2[0], k2[1]);
        kk = u64max(kk, dpp_shr_u64<0x111>(kk));
        kk = u64max(kk, dpp_shr_u64<0x112>(kk));
        kk = u64max(kk, dpp_shr_u64<0x114>(kk));
        kk = u64max(kk, dpp_shr_u64<0x118>(kk));
        const unsigned blo =
            (unsigned)__builtin_amdgcn_readlane((int)(unsigned)kk, 15);
        const int last = 8191 - (int)(blo & 0x1FFFu);

        const float4 cc = sxyz[last];
        lx = cc.x; ly = cc.y; lz = cc.z;
        if (t == 0) {
            float* c = centers + ((size_t)b * G_ + g) * 3;
            c[0] = lx; c[1] = ly; c[2] = lz;
        }
    }
}

// ---------------------------------------------------------------------------
// Kernel 2: kNN v2 — wave-local top-32, barrier-free round loop.
// 4 waves x 2048-point slices; 32 pts/lane in regs; per-round pure-DPP u64
// min-reduce (update_dpp keeps old on unwritten lanes -> min-safe) +
// readlane(63). Winner rescans ONE 8-elem group (hierarchical mins gm0..gm3,
// compile-time indexing via switch). 4 sorted lists merged exactly by
// parallel rank-merge (binary searches; keys unique). One barrier total.
// ---------------------------------------------------------------------------
__global__ __launch_bounds__(256) void knn_kernel(const float* __restrict__ pts,
                                                  const float* __restrict__ centers,
                                                  float* __restrict__ neigh) {
    __shared__ unsigned long long wkeys[4][32];
    __shared__ int midx[32];

    const int cid = blockIdx.x;
    const int b = cid >> 9;
    const int t = threadIdx.x;
    const int w = t >> 6;
    const int l = t & 63;
    const float* p = pts + (size_t)b * (N_ * 3);
    const float* c = centers + (size_t)cid * 3;
    const float cx = c[0], cy = c[1], cz = c[2];

    const int iy0 = (w << 11) + l;  // this lane's base point index

    unsigned int db[32];
#pragma unroll
    for (int i = 0; i < 32; ++i) {
        const int idx = iy0 + (i << 6);
        const float dx = __fsub_rn(p[3 * idx + 0], cx);
        const float dy = __fsub_rn(p[3 * idx + 1], cy);
        const float dz = __fsub_rn(p[3 * idx + 2], cz);
        const float d = __fadd_rn(__fadd_rn(__fmul_rn(dx, dx), __fmul_rn(dy, dy)),
                                  __fmul_rn(dz, dz));
        db[i] = __float_as_uint(d);
    }

    unsigned int excl = 0u;
    unsigned long long gm0, gm1, gm2, gm3;

#define KNN_SCAN_GROUP(G, DEST)                                               \
    {                                                                         \
        unsigned long long nm = ~0ull;                                        \
        _Pragma("unroll") for (int j = 0; j < 8; ++j) {                       \
            const int i = ((G) << 3) + j;                                     \
            if (!(excl & (1u << i))) {                                        \
                const unsigned long long k2 =                                 \
                    ((unsigned long long)db[i] << 13) |                       \
                    (unsigned long long)(unsigned)(iy0 + (i << 6));           \
                nm = (nm < k2) ? nm : k2;                                     \
            }                                                                 \
        }                                                                     \
        DEST = nm;                                                            \
    }

    KNN_SCAN_GROUP(0, gm0)
    KNN_SCAN_GROUP(1, gm1)
    KNN_SCAN_GROUP(2, gm2)
    KNN_SCAN_GROUP(3, gm3)
    unsigned long long lkey = u64min(u64min(gm0, gm1), u64min(gm2, gm3));

    for (int r = 0; r < K_; ++r) {
        // full-wave min: row_shr 1/2/4/8 then row_bcast15/31 -> lane 63
        unsigned long long x = lkey;
        x = u64min(x, dpp_upd_u64<0x111>(x));
        x = u64min(x, dpp_upd_u64<0x112>(x));
        x = u64min(x, dpp_upd_u64<0x114>(x));
        x = u64min(x, dpp_upd_u64<0x118>(x));
        x = u64min(x, dpp_upd_u64<0x142>(x));  // row_bcast15
        x = u64min(x, dpp_upd_u64<0x143>(x));  // row_bcast31
        const unsigned blo = (unsigned)__builtin_amdgcn_readlane((int)(unsigned)x, 63);
        const unsigned bhi =
            (unsigned)__builtin_amdgcn_readlane((int)(unsigned)(x >> 32), 63);
        const unsigned long long best = ((unsigned long long)bhi << 32) | blo;

        if (best == lkey) {  // unique winner lane
            const int i = ((int)(best & 0x1FFFull) >> 6) & 31;
            excl |= 1u << i;
            switch (i >> 3) {
                case 0: KNN_SCAN_GROUP(0, gm0) break;
                case 1: KNN_SCAN_GROUP(1, gm1) break;
                case 2: KNN_SCAN_GROUP(2, gm2) break;
                default: KNN_SCAN_GROUP(3, gm3) break;
            }
            lkey = u64min(u64min(gm0, gm1), u64min(gm2, gm3));
        }
        if (l == 0) wkeys[w][r] = best;
    }
#undef KNN_SCAN_GROUP
    __syncthreads();

    // parallel rank-merge of 4 sorted 32-lists (keys unique -> strict less)
    if (t < 128) {
        const int wv = t >> 5;
        const int pos = t & 31;
        const unsigned long long mykey = wkeys[wv][pos];
        int rank = pos;
#pragma unroll
        for (int d = 1; d < 4; ++d) {
            const int ol = (wv + d) & 3;
            int cnt = 0;
#pragma unroll
            for (int s = 32; s >= 1; s >>= 1) {
                const int n = cnt + s;
                if (n <= 32 && wkeys[ol][n - 1] < mykey) cnt = n;
            }
            rank += cnt;
        }
        if (rank < 32) midx[rank] = (int)(mykey & 0x1FFFull);
    }
    __syncthreads();

    if (t < 32) {
        const int idx = midx[t];
        float* o3 = neigh + (((size_t)cid * K_) + t) * 3;
        o3[0] = __fsub_rn(p[3 * idx + 0], cx);
        o3[1] = __fsub_rn(p[3 * idx + 1], cy);
        o3[2] = __fsub_rn(p[3 * idx + 2], cz);
    }
}

// ---------------------------------------------------------------------------
// Kernel 3: MFMA MLP (unchanged from R4). 512 thr x 256 points/block.
// ---------------------------------------------------------------------------
__global__ __launch_bounds__(512) void mlp_kernel(
    const float* __restrict__ neigh, const float* __restrict__ W0b,
    const float* __restrict__ b1b, const float* __restrict__ b2b,
    const short* __restrict__ W1b, const short* __restrict__ W2b,
    float* __restrict__ out) {
    __shared__ bf16x8 lw1v[1024];        // 16KB  W1' [128][64] bf16, swizzled
    __shared__ bf16x8 lw2v[4096];        // 64KB  W2' [256][128] bf16, swizzled
    __shared__ bf16x8 lh2v[8 * 512];     // 64KB  per-wave h2 [32][128] bf16, swizzled
    __shared__ float lw0[256];           // 1KB   W0' [64][4] (wx,wy,wz,bias)
    __shared__ float lb1[128];
    __shared__ float lb2[256];
    __shared__ float colmax[256];

    const int t = threadIdx.x;
    const int w = t >> 6;
    const int l = t & 63;
    const int lr = l & 15;
    const int lg = l >> 4;

    {
        char* d1 = (char*)lw1v;
        for (int i = t; i < 1024; i += 512) {
            const int d = i * 16;
            const int src = d ^ ((((unsigned)d >> 7) & 7) << 4);
            *(bf16x8*)(d1 + d) = *(const bf16x8*)((const char*)W1b + src);
        }
        char* d2 = (char*)lw2v;
        for (int i = t; i < 4096; i += 512) {
            const int d = i * 16;
            const int src = d ^ ((((unsigned)d >> 8) & 7) << 4);
            *(bf16x8*)(d2 + d) = *(const bf16x8*)((const char*)W2b + src);
        }
        if (t < 256) lw0[t] = W0b[t];
        if (t < 128) lb1[t] = b1b[t];
        if (t < 256) lb2[t] = b2b[t];
        if (t < 256) colmax[t] = 0.0f;
    }
    __syncthreads();

    const size_t pbase = (size_t)blockIdx.x * 256 + w * 32;
    bf16x8 a1[2][2];
#pragma unroll
    for (int m = 0; m < 2; ++m) {
        const float* pp = neigh + (pbase + m * 16 + lr) * 3;
        const float x0 = pp[0], x1 = pp[1], x2 = pp[2];
#pragma unroll
        for (int s = 0; s < 2; ++s) {
            bf16x8 v;
#pragma unroll
            for (int j = 0; j < 8; ++j) {
                const int c = s * 32 + lg * 8 + j;
                const float4 wv = *(const float4*)&lw0[c * 4];
                float val = fmaf(x2, wv.z, fmaf(x1, wv.y, x0 * wv.x)) + wv.w;
                v[j] = f2bf(fmaxf(val, 0.0f));
            }
            a1[m][s] = v;
        }
    }

    const f32x4 vzero = {0.f, 0.f, 0.f, 0.f};
    f32x4 acc2[2][8];
#pragma unroll
    for (int m = 0; m < 2; ++m)
#pragma unroll
        for (int n = 0; n < 8; ++n) acc2[m][n] = vzero;

    const char* w1p = (const char*)lw1v;
#pragma unroll
    for (int s = 0; s < 2; ++s) {
#pragma unroll
        for (int n = 0; n < 8; ++n) {
            const int o = n * 16 + lr;
            int byte = o * 128 + s * 64 + lg * 16;
            byte ^= ((o & 7) << 4);
            const bf16x8 bfr = *(const bf16x8*)(w1p + byte);
            acc2[0][n] = __builtin_amdgcn_mfma_f32_16x16x32_bf16(a1[0][s], bfr, acc2[0][n], 0, 0, 0);
            acc2[1][n] = __builtin_amdgcn_mfma_f32_16x16x32_bf16(a1[1][s], bfr, acc2[1][n], 0, 0, 0);
        }
    }

    char* myh2 = (char*)(lh2v + w * 512);
#pragma unroll
    for (int m = 0; m < 2; ++m)
#pragma unroll
        for (int n = 0; n < 8; ++n) {
            const int o = n * 16 + lr;
            const float bb = lb1[o];
#pragma unroll
            for (int q = 0; q < 4; ++q) {
                const int row = m * 16 + lg * 4 + q;
                int byte = row * 256 + o * 2;
                byte ^= ((row & 7) << 4);
                *(short*)(myh2 + byte) = f2bf(fmaxf(acc2[m][n][q] + bb, 0.0f));
            }
        }

    f32x4 acc3[2][16];
#pragma unroll
    for (int m = 0; m < 2; ++m)
#pragma unroll
        for (int n = 0; n < 16; ++n) acc3[m][n] = vzero;

    const char* w2p = (const char*)lw2v;
#pragma unroll
    for (int s = 0; s < 4; ++s) {
        bf16x8 a[2];
#pragma unroll
        for (int m = 0; m < 2; ++m) {
            const int row = m * 16 + lr;
            int byte = row * 256 + s * 64 + lg * 16;
            byte ^= ((row & 7) << 4);
            a[m] = *(const bf16x8*)(myh2 + byte);
        }
#pragma unroll
        for (int n = 0; n < 16; ++n) {
            const int o = n * 16 + lr;
            int byte = o * 256 + s * 64 + lg * 16;
            byte ^= ((o & 7) << 4);
            const bf16x8 bfr = *(const bf16x8*)(w2p + byte);
            acc3[0][n] = __builtin_amdgcn_mfma_f32_16x16x32_bf16(a[0], bfr, acc3[0][n], 0, 0, 0);
            acc3[1][n] = __builtin_amdgcn_mfma_f32_16x16x32_bf16(a[1], bfr, acc3[1][n], 0, 0, 0);
        }
    }

#pragma unroll
    for (int n = 0; n < 16; ++n) {
        const int o = n * 16 + lr;
        const float bb = lb2[o];
        float mx = 0.0f;
#pragma unroll
        for (int m = 0; m < 2; ++m)
#pragma unroll
            for (int q = 0; q < 4; ++q) mx = fmaxf(mx, acc3[m][n][q] + bb);
        mx = fmaxf(mx, 0.0f);
        mx = fmaxf(mx, __shfl_xor(mx, 16, 64));
        mx = fmaxf(mx, __shfl_xor(mx, 32, 64));
        if (lg == 0) atomicMax((unsigned int*)&colmax[o], __float_as_uint(mx));
    }
    __syncthreads();
    if (t < 256) {
        const int b = (int)(blockIdx.x >> 6);
        atomicMax((unsigned int*)out + b * 256 + t, __float_as_uint(colmax[t]));
    }
}

// ---------------------------------------------------------------------------
extern "C" void kernel_launch(void* const* d_in, const int* in_sizes, int n_in,
                              void* d_out, int out_size, void* d_ws, size_t ws_size,
                              hipStream_t stream) {
    const float* pts = (const float*)d_in[0];
    const float* w0 = (const float*)d_in[1];
    const float* b0 = (const float*)d_in[2];
    const float* g0 = (const float*)d_in[3];
    const float* be0 = (const float*)d_in[4];
    const float* m0 = (const float*)d_in[5];
    const float* v0 = (const float*)d_in[6];
    const float* w1 = (const float*)d_in[7];
    const float* b1 = (const float*)d_in[8];
    const float* g1 = (const float*)d_in[9];
    const float* be1 = (const float*)d_in[10];
    const float* m1 = (const float*)d_in[11];
    const float* v1 = (const float*)d_in[12];
    const float* w2 = (const float*)d_in[13];
    const float* b2 = (const float*)d_in[14];
    const float* g2 = (const float*)d_in[15];
    const float* be2 = (const float*)d_in[16];
    const float* m2 = (const float*)d_in[17];
    const float* v2 = (const float*)d_in[18];

    char* ws = (char*)d_ws;
    float* centers = (float*)ws;                        // 192KB @ 0
    float* neigh = (float*)(ws + (size_t)262144);       // 6.29MB
    char* wb = ws + (size_t)6553600;                    // weights region
    float* W0b = (float*)(wb + 0);                      // 1KB
    float* b1b = (float*)(wb + 1024);                   // 512B
    float* b2b = (float*)(wb + 1536);                   // 1KB
    short* W1b = (short*)(wb + 2560);                   // 16KB
    short* W2b = (short*)(wb + 2560 + 16384);           // 64KB

    hipMemsetAsync(d_out, 0, (size_t)out_size * sizeof(float), stream);
    prep_kernel<<<1, 256, 0, stream>>>(w0, b0, g0, be0, m0, v0,
                                       w1, b1, g1, be1, m1, v1,
                                       w2, b2, g2, be2, m2, v2,
                                       W0b, b1b, b2b, W1b, W2b);
    fps_kernel<<<B_, 512, 0, stream>>>(pts, centers);
    knn_kernel<<<B_ * G_, 256, 0, stream>>>(pts, centers, neigh);
    mlp_kernel<<<(B_ * G_ * K_) / 256, 512, 0, stream>>>(
        neigh, W0b, b1b, b2b, W1b, W2b, (float*)d_out);
}

// Round 6
// 926.905 us; speedup vs baseline: 2.1774x; 1.0016x over previous
//
#include <hip/hip_runtime.h>

#define B_ 32
#define N_ 8192
#define G_ 512
#define K_ 32
#define EPSF 1e-5f

typedef __attribute__((ext_vector_type(8))) short bf16x8;
typedef __attribute__((ext_vector_type(4))) float f32x4;
typedef __attribute__((ext_vector_type(2))) float f32x2;
typedef __attribute__((ext_vector_type(2))) unsigned long long u64x2;

static __device__ __forceinline__ short f2bf(float f) {
    unsigned u = __float_as_uint(f);
    u += 0x7fffu + ((u >> 16) & 1u);  // round-to-nearest-even
    return (short)(u >> 16);
}

static __device__ __forceinline__ unsigned long long u64max(unsigned long long a,
                                                            unsigned long long b) {
    return a > b ? a : b;
}
static __device__ __forceinline__ unsigned long long u64min(unsigned long long a,
                                                            unsigned long long b) {
    return a < b ? a : b;
}

// DPP row_shr:<N> move of a u64, 0-fill (max-neutral for non-negative keys).
template <int CTL>
static __device__ __forceinline__ unsigned long long dpp_shr_u64(unsigned long long k) {
    const int lo = __builtin_amdgcn_mov_dpp((int)(unsigned)k, CTL, 0xf, 0xf, true);
    const int hi = __builtin_amdgcn_mov_dpp((int)(unsigned)(k >> 32), CTL, 0xf, 0xf, true);
    return ((unsigned long long)(unsigned)hi << 32) | (unsigned)lo;
}

// DPP move of a u64 that PRESERVES the old value on unwritten/invalid lanes
// (bound_ctrl=false, old=own key) -> safe for MIN reductions (no 0-fill).
template <int CTL>
static __device__ __forceinline__ unsigned long long dpp_upd_u64(unsigned long long k) {
    const int lo = __builtin_amdgcn_update_dpp((int)(unsigned)k, (int)(unsigned)k,
                                               CTL, 0xf, 0xf, false);
    const int hi = __builtin_amdgcn_update_dpp((int)(unsigned)(k >> 32),
                                               (int)(unsigned)(k >> 32),
                                               CTL, 0xf, 0xf, false);
    return ((unsigned long long)(unsigned)hi << 32) | (unsigned)lo;
}

// ---------------------------------------------------------------------------
// Prep: fold BN (inference) into weights/biases once.
// ---------------------------------------------------------------------------
__global__ __launch_bounds__(256) void prep_kernel(
    const float* __restrict__ w0, const float* __restrict__ b0,
    const float* __restrict__ g0, const float* __restrict__ be0,
    const float* __restrict__ m0, const float* __restrict__ v0,
    const float* __restrict__ w1, const float* __restrict__ b1,
    const float* __restrict__ g1, const float* __restrict__ be1,
    const float* __restrict__ m1, const float* __restrict__ v1,
    const float* __restrict__ w2, const float* __restrict__ b2,
    const float* __restrict__ g2, const float* __restrict__ be2,
    const float* __restrict__ m2, const float* __restrict__ v2,
    float* __restrict__ W0b, float* __restrict__ b1b, float* __restrict__ b2b,
    short* __restrict__ W1b, short* __restrict__ W2b) {
    const int t = threadIdx.x;
    if (t < 64) {
        const float sc = g0[t] / sqrtf(v0[t] + EPSF);
        W0b[t * 4 + 0] = w0[t * 3 + 0] * sc;
        W0b[t * 4 + 1] = w0[t * 3 + 1] * sc;
        W0b[t * 4 + 2] = w0[t * 3 + 2] * sc;
        W0b[t * 4 + 3] = (b0[t] - m0[t]) * sc + be0[t];
    }
    if (t < 128) b1b[t] = (b1[t] - m1[t]) * (g1[t] / sqrtf(v1[t] + EPSF)) + be1[t];
    if (t < 256) b2b[t] = (b2[t] - m2[t]) * (g2[t] / sqrtf(v2[t] + EPSF)) + be2[t];
    for (int i = t; i < 128 * 64; i += 256) {
        const int o = i >> 6;
        const float sc = g1[o] / sqrtf(v1[o] + EPSF);
        W1b[i] = f2bf(w1[i] * sc);
    }
    for (int i = t; i < 256 * 128; i += 256) {
        const int o = i >> 7;
        const float sc = g2[o] / sqrtf(v2[o] + EPSF);
        W2b[i] = f2bf(w2[i] * sc);
    }
}

// ---------------------------------------------------------------------------
// Kernel 1: FPS v4 — packed-fp32 distance loop, 256 thr (1 wave/SIMD).
// 32 pts/thread as 16 float2 pairs. dx = px + (-lx) (exact), d = (dx²+dy²)+dz²
// with contraction OFF (bit-identical to __fsub_rn/__fmul_rn/__fadd_rn form).
// Reduce skeleton identical to R4/R5 (proven): 4-level row_shr -> 16 rowkeys
// in LDS -> per-wave redundant 8-lane reduce -> readlane(7) -> sxyz broadcast.
// Key = (dist_bits<<13) | (8191-idx): max-reduce == argmax, first-index ties.
// ---------------------------------------------------------------------------
__global__ __launch_bounds__(256) void fps_kernel(const float* __restrict__ pts,
                                                  float* __restrict__ centers) {
    __shared__ float4 sxyz[N_];  // 128KB
    __shared__ __align__(16) unsigned long long rowkeys[2][16];

    const int b = blockIdx.x;
    const int t = threadIdx.x;
    const int l = t & 63;
    const int w = t >> 6;
    const float* p = pts + (size_t)b * (N_ * 3);

    f32x2 px[16], py[16], pz[16], md[16];
#pragma unroll
    for (int i = 0; i < 16; ++i) {
        const int i0 = t + (2 * i) * 256;
        const int i1 = i0 + 256;
        px[i] = f32x2{p[3 * i0 + 0], p[3 * i1 + 0]};
        py[i] = f32x2{p[3 * i0 + 1], p[3 * i1 + 1]};
        pz[i] = f32x2{p[3 * i0 + 2], p[3 * i1 + 2]};
        sxyz[i0] = make_float4(px[i][0], py[i][0], pz[i][0], 0.0f);
        sxyz[i1] = make_float4(px[i][1], py[i][1], pz[i][1], 0.0f);
        md[i] = f32x2{1e10f, 1e10f};
    }
    __syncthreads();

    if (t == 0) {
        float* c = centers + (size_t)b * (G_ * 3);
        c[0] = px[0][0]; c[1] = py[0][0]; c[2] = pz[0][0];  // idx 0
    }
    const float4 c0 = sxyz[0];
    float lx = c0.x, ly = c0.y, lz = c0.z;
    const int pay0 = 8191 - t;  // idx = t + j*256 -> pay = pay0 - (j<<8)

    for (int g = 1; g < G_; ++g) {
        const f32x2 nlx = {-lx, -lx};
        const f32x2 nly = {-ly, -ly};
        const f32x2 nlz = {-lz, -lz};
        float m_best = -1.0f;
        int j_best = 0;
        {
#pragma clang fp contract(off)
#pragma unroll
            for (int i = 0; i < 16; ++i) {
                const f32x2 dx = px[i] + nlx;  // == px - lx exactly
                const f32x2 dy = py[i] + nly;
                const f32x2 dz = pz[i] + nlz;
                const f32x2 d = (dx * dx + dy * dy) + dz * dz;
                const f32x2 m = __builtin_elementwise_min(md[i], d);
                md[i] = m;
                const bool c0_ = m[0] > m_best;  // strict: first-index ties
                m_best = c0_ ? m[0] : m_best;
                j_best = c0_ ? 2 * i : j_best;
                const bool c1_ = m[1] > m_best;
                m_best = c1_ ? m[1] : m_best;
                j_best = c1_ ? 2 * i + 1 : j_best;
            }
        }
        unsigned long long key =
            ((unsigned long long)__float_as_uint(m_best) << 13) |
            (unsigned long long)(unsigned)(pay0 - (j_best << 8));

        // stage 1: reduce within 16-lane rows; row max lands in lane 15
        key = u64max(key, dpp_shr_u64<0x111>(key));
        key = u64max(key, dpp_shr_u64<0x112>(key));
        key = u64max(key, dpp_shr_u64<0x114>(key));
        key = u64max(key, dpp_shr_u64<0x118>(key));
        if ((l & 15) == 15) rowkeys[g & 1][w * 4 + (l >> 4)] = key;  // 16 rows
        __syncthreads();

        // stage 2: every wave redundantly reduces the 16 row-keys
        const u64x2* rk = (const u64x2*)&rowkeys[g & 1][0];
        const u64x2 k2 = rk[l & 7];
        unsigned long long kk = u64max(k2[0], k2[1]);
        kk = u64max(kk, dpp_shr_u64<0x111>(kk));
        kk = u64max(kk, dpp_shr_u64<0x112>(kk));
        kk = u64max(kk, dpp_shr_u64<0x114>(kk));
        const unsigned blo =
            (unsigned)__builtin_amdgcn_readlane((int)(unsigned)kk, 7);
        const int last = 8191 - (int)(blo & 0x1FFFu);

        const float4 cc = sxyz[last];  // broadcast read
        lx = cc.x; ly = cc.y; lz = cc.z;
        if (t == 0) {
            float* c = centers + ((size_t)b * G_ + g) * 3;
            c[0] = lx; c[1] = ly; c[2] = lz;
        }
    }
}

// ---------------------------------------------------------------------------
// Kernel 2: kNN v2 (unchanged from R5 — passed). Wave-local top-32 via DPP,
// hierarchical rescan, parallel rank-merge.
// ---------------------------------------------------------------------------
__global__ __launch_bounds__(256) void knn_kernel(const float* __restrict__ pts,
                                                  const float* __restrict__ centers,
                                                  float* __restrict__ neigh) {
    __shared__ unsigned long long wkeys[4][32];
    __shared__ int midx[32];

    const int cid = blockIdx.x;
    const int b = cid >> 9;
    const int t = threadIdx.x;
    const int w = t >> 6;
    const int l = t & 63;
    const float* p = pts + (size_t)b * (N_ * 3);
    const float* c = centers + (size_t)cid * 3;
    const float cx = c[0], cy = c[1], cz = c[2];

    const int iy0 = (w << 11) + l;

    unsigned int db[32];
#pragma unroll
    for (int i = 0; i < 32; ++i) {
        const int idx = iy0 + (i << 6);
        const float dx = __fsub_rn(p[3 * idx + 0], cx);
        const float dy = __fsub_rn(p[3 * idx + 1], cy);
        const float dz = __fsub_rn(p[3 * idx + 2], cz);
        const float d = __fadd_rn(__fadd_rn(__fmul_rn(dx, dx), __fmul_rn(dy, dy)),
                                  __fmul_rn(dz, dz));
        db[i] = __float_as_uint(d);
    }

    unsigned int excl = 0u;
    unsigned long long gm0, gm1, gm2, gm3;

#define KNN_SCAN_GROUP(G, DEST)                                               \
    {                                                                         \
        unsigned long long nm = ~0ull;                                        \
        _Pragma("unroll") for (int j = 0; j < 8; ++j) {                       \
            const int i = ((G) << 3) + j;                                     \
            if (!(excl & (1u << i))) {                                        \
                const unsigned long long k2 =                                 \
                    ((unsigned long long)db[i] << 13) |                       \
                    (unsigned long long)(unsigned)(iy0 + (i << 6));           \
                nm = (nm < k2) ? nm : k2;                                     \
            }                                                                 \
        }                                                                     \
        DEST = nm;                                                            \
    }

    KNN_SCAN_GROUP(0, gm0)
    KNN_SCAN_GROUP(1, gm1)
    KNN_SCAN_GROUP(2, gm2)
    KNN_SCAN_GROUP(3, gm3)
    unsigned long long lkey = u64min(u64min(gm0, gm1), u64min(gm2, gm3));

    for (int r = 0; r < K_; ++r) {
        unsigned long long x = lkey;
        x = u64min(x, dpp_upd_u64<0x111>(x));
        x = u64min(x, dpp_upd_u64<0x112>(x));
        x = u64min(x, dpp_upd_u64<0x114>(x));
        x = u64min(x, dpp_upd_u64<0x118>(x));
        x = u64min(x, dpp_upd_u64<0x142>(x));  // row_bcast15
        x = u64min(x, dpp_upd_u64<0x143>(x));  // row_bcast31
        const unsigned blo = (unsigned)__builtin_amdgcn_readlane((int)(unsigned)x, 63);
        const unsigned bhi =
            (unsigned)__builtin_amdgcn_readlane((int)(unsigned)(x >> 32), 63);
        const unsigned long long best = ((unsigned long long)bhi << 32) | blo;

        if (best == lkey) {
            const int i = ((int)(best & 0x1FFFull) >> 6) & 31;
            excl |= 1u << i;
            switch (i >> 3) {
                case 0: KNN_SCAN_GROUP(0, gm0) break;
                case 1: KNN_SCAN_GROUP(1, gm1) break;
                case 2: KNN_SCAN_GROUP(2, gm2) break;
                default: KNN_SCAN_GROUP(3, gm3) break;
            }
            lkey = u64min(u64min(gm0, gm1), u64min(gm2, gm3));
        }
        if (l == 0) wkeys[w][r] = best;
    }
#undef KNN_SCAN_GROUP
    __syncthreads();

    if (t < 128) {
        const int wv = t >> 5;
        const int pos = t & 31;
        const unsigned long long mykey = wkeys[wv][pos];
        int rank = pos;
#pragma unroll
        for (int d = 1; d < 4; ++d) {
            const int ol = (wv + d) & 3;
            int cnt = 0;
#pragma unroll
            for (int s = 32; s >= 1; s >>= 1) {
                const int n = cnt + s;
                if (n <= 32 && wkeys[ol][n - 1] < mykey) cnt = n;
            }
            rank += cnt;
        }
        if (rank < 32) midx[rank] = (int)(mykey & 0x1FFFull);
    }
    __syncthreads();

    if (t < 32) {
        const int idx = midx[t];
        float* o3 = neigh + (((size_t)cid * K_) + t) * 3;
        o3[0] = __fsub_rn(p[3 * idx + 0], cx);
        o3[1] = __fsub_rn(p[3 * idx + 1], cy);
        o3[2] = __fsub_rn(p[3 * idx + 2], cz);
    }
}

// ---------------------------------------------------------------------------
// Kernel 3: MFMA MLP (unchanged from R4/R5). 512 thr x 256 points/block.
// ---------------------------------------------------------------------------
__global__ __launch_bounds__(512) void mlp_kernel(
    const float* __restrict__ neigh, const float* __restrict__ W0b,
    const float* __restrict__ b1b, const float* __restrict__ b2b,
    const short* __restrict__ W1b, const short* __restrict__ W2b,
    float* __restrict__ out) {
    __shared__ bf16x8 lw1v[1024];
    __shared__ bf16x8 lw2v[4096];
    __shared__ bf16x8 lh2v[8 * 512];
    __shared__ float lw0[256];
    __shared__ float lb1[128];
    __shared__ float lb2[256];
    __shared__ float colmax[256];

    const int t = threadIdx.x;
    const int w = t >> 6;
    const int l = t & 63;
    const int lr = l & 15;
    const int lg = l >> 4;

    {
        char* d1 = (char*)lw1v;
        for (int i = t; i < 1024; i += 512) {
            const int d = i * 16;
            const int src = d ^ ((((unsigned)d >> 7) & 7) << 4);
            *(bf16x8*)(d1 + d) = *(const bf16x8*)((const char*)W1b + src);
        }
        char* d2 = (char*)lw2v;
        for (int i = t; i < 4096; i += 512) {
            const int d = i * 16;
            const int src = d ^ ((((unsigned)d >> 8) & 7) << 4);
            *(bf16x8*)(d2 + d) = *(const bf16x8*)((const char*)W2b + src);
        }
        if (t < 256) lw0[t] = W0b[t];
        if (t < 128) lb1[t] = b1b[t];
        if (t < 256) lb2[t] = b2b[t];
        if (t < 256) colmax[t] = 0.0f;
    }
    __syncthreads();

    const size_t pbase = (size_t)blockIdx.x * 256 + w * 32;
    bf16x8 a1[2][2];
#pragma unroll
    for (int m = 0; m < 2; ++m) {
        const float* pp = neigh + (pbase + m * 16 + lr) * 3;
        const float x0 = pp[0], x1 = pp[1], x2 = pp[2];
#pragma unroll
        for (int s = 0; s < 2; ++s) {
            bf16x8 v;
#pragma unroll
            for (int j = 0; j < 8; ++j) {
                const int c = s * 32 + lg * 8 + j;
                const float4 wv = *(const float4*)&lw0[c * 4];
                float val = fmaf(x2, wv.z, fmaf(x1, wv.y, x0 * wv.x)) + wv.w;
                v[j] = f2bf(fmaxf(val, 0.0f));
            }
            a1[m][s] = v;
        }
    }

    const f32x4 vzero = {0.f, 0.f, 0.f, 0.f};
    f32x4 acc2[2][8];
#pragma unroll
    for (int m = 0; m < 2; ++m)
#pragma unroll
        for (int n = 0; n < 8; ++n) acc2[m][n] = vzero;

    const char* w1p = (const char*)lw1v;
#pragma unroll
    for (int s = 0; s < 2; ++s) {
#pragma unroll
        for (int n = 0; n < 8; ++n) {
            const int o = n * 16 + lr;
            int byte = o * 128 + s * 64 + lg * 16;
            byte ^= ((o & 7) << 4);
            const bf16x8 bfr = *(const bf16x8*)(w1p + byte);
            acc2[0][n] = __builtin_amdgcn_mfma_f32_16x16x32_bf16(a1[0][s], bfr, acc2[0][n], 0, 0, 0);
            acc2[1][n] = __builtin_amdgcn_mfma_f32_16x16x32_bf16(a1[1][s], bfr, acc2[1][n], 0, 0, 0);
        }
    }

    char* myh2 = (char*)(lh2v + w * 512);
#pragma unroll
    for (int m = 0; m < 2; ++m)
#pragma unroll
        for (int n = 0; n < 8; ++n) {
            const int o = n * 16 + lr;
            const float bb = lb1[o];
#pragma unroll
            for (int q = 0; q < 4; ++q) {
                const int row = m * 16 + lg * 4 + q;
                int byte = row * 256 + o * 2;
                byte ^= ((row & 7) << 4);
                *(short*)(myh2 + byte) = f2bf(fmaxf(acc2[m][n][q] + bb, 0.0f));
            }
        }

    f32x4 acc3[2][16];
#pragma unroll
    for (int m = 0; m < 2; ++m)
#pragma unroll
        for (int n = 0; n < 16; ++n) acc3[m][n] = vzero;

    const char* w2p = (const char*)lw2v;
#pragma unroll
    for (int s = 0; s < 4; ++s) {
        bf16x8 a[2];
#pragma unroll
        for (int m = 0; m < 2; ++m) {
            const int row = m * 16 + lr;
            int byte = row * 256 + s * 64 + lg * 16;
            byte ^= ((row & 7) << 4);
            a[m] = *(const bf16x8*)(myh2 + byte);
        }
#pragma unroll
        for (int n = 0; n < 16; ++n) {
            const int o = n * 16 + lr;
            int byte = o * 256 + s * 64 + lg * 16;
            byte ^= ((o & 7) << 4);
            const bf16x8 bfr = *(const bf16x8*)(w2p + byte);
            acc3[0][n] = __builtin_amdgcn_mfma_f32_16x16x32_bf16(a[0], bfr, acc3[0][n], 0, 0, 0);
            acc3[1][n] = __builtin_amdgcn_mfma_f32_16x16x32_bf16(a[1], bfr, acc3[1][n], 0, 0, 0);
        }
    }

#pragma unroll
    for (int n = 0; n < 16; ++n) {
        const int o = n * 16 + lr;
        const float bb = lb2[o];
        float mx = 0.0f;
#pragma unroll
        for (int m = 0; m < 2; ++m)
#pragma unroll
            for (int q = 0; q < 4; ++q) mx = fmaxf(mx, acc3[m][n][q] + bb);
        mx = fmaxf(mx, 0.0f);
        mx = fmaxf(mx, __shfl_xor(mx, 16, 64));
        mx = fmaxf(mx, __shfl_xor(mx, 32, 64));
        if (lg == 0) atomicMax((unsigned int*)&colmax[o], __float_as_uint(mx));
    }
    __syncthreads();
    if (t < 256) {
        const int b = (int)(blockIdx.x >> 6);
        atomicMax((unsigned int*)out + b * 256 + t, __float_as_uint(colmax[t]));
    }
}

// ---------------------------------------------------------------------------
extern "C" void kernel_launch(void* const* d_in, const int* in_sizes, int n_in,
                              void* d_out, int out_size, void* d_ws, size_t ws_size,
                              hipStream_t stream) {
    const float* pts = (const float*)d_in[0];
    const float* w0 = (const float*)d_in[1];
    const float* b0 = (const float*)d_in[2];
    const float* g0 = (const float*)d_in[3];
    const float* be0 = (const float*)d_in[4];
    const float* m0 = (const float*)d_in[5];
    const float* v0 = (const float*)d_in[6];
    const float* w1 = (const float*)d_in[7];
    const float* b1 = (const float*)d_in[8];
    const float* g1 = (const float*)d_in[9];
    const float* be1 = (const float*)d_in[10];
    const float* m1 = (const float*)d_in[11];
    const float* v1 = (const float*)d_in[12];
    const float* w2 = (const float*)d_in[13];
    const float* b2 = (const float*)d_in[14];
    const float* g2 = (const float*)d_in[15];
    const float* be2 = (const float*)d_in[16];
    const float* m2 = (const float*)d_in[17];
    const float* v2 = (const float*)d_in[18];

    char* ws = (char*)d_ws;
    float* centers = (float*)ws;                        // 192KB @ 0
    float* neigh = (float*)(ws + (size_t)262144);       // 6.29MB
    char* wb = ws + (size_t)6553600;                    // weights region
    float* W0b = (float*)(wb + 0);                      // 1KB
    float* b1b = (float*)(wb + 1024);                   // 512B
    float* b2b = (float*)(wb + 1536);                   // 1KB
    short* W1b = (short*)(wb + 2560);                   // 16KB
    short* W2b = (short*)(wb + 2560 + 16384);           // 64KB

    hipMemsetAsync(d_out, 0, (size_t)out_size * sizeof(float), stream);
    prep_kernel<<<1, 256, 0, stream>>>(w0, b0, g0, be0, m0, v0,
                                       w1, b1, g1, be1, m1, v1,
                                       w2, b2, g2, be2, m2, v2,
                                       W0b, b1b, b2b, W1b, W2b);
    fps_kernel<<<B_, 256, 0, stream>>>(pts, centers);
    knn_kernel<<<B_ * G_, 256, 0, stream>>>(pts, centers, neigh);
    mlp_kernel<<<(B_ * G_ * K_) / 256, 512, 0, stream>>>(
        neigh, W0b, b1b, b2b, W1b, W2b, (float*)d_out);
}